// Round 1
// baseline (1644.835 us; speedup 1.0000x reference)
//
#include <hip/hip_runtime.h>
#include <cmath>

// Problem constants
#define NNODES 50000
#define NEDGES 800000
#define IND    512
#define HD     128
#define CD     64

// ---------------- workspace layout (float offsets) ----------------
// region1 (h1, 25,600,000 floats) later reused for xw / xj / hidden
static const long H1_OFF      = 0;            // 50000*512
static const long XW_OFF      = 0;            // 50000*128   (after h1 dead)
static const long XJ_OFF      = 6400000;      // 50000*256
static const long HID_OFF     = 19200000;     // 50000*128
// region2 (h2) later reused for CSR
static const long H2_OFF      = 25600000;     // 50000*64
static const long CSR_ROW_OFF = 25600000;     // 800000 ints (after h2 dead)
static const long CSR_W_OFF   = 26400000;     // 800000 floats
static const long LOGITS_OFF  = 28800000;     // 50000*64
static const long PE_OFF      = 32000000;     // 50000*64
static const long EWR_OFF     = 35200000;     // 800000 (raw ew; later reused as scan tmp ints)
static const long EW_OFF      = 36000000;     // 800000
static const long DEG_OFF     = 36800000;     // 50000
static const long DIS_OFF     = 36850000;     // 50000
static const long CNT_OFF     = 36900000;     // 50000 ints
static const long RP_OFF      = 36950000;     // 50001 ints
static const long WOFF_OFF    = 37000004;     // 50000 ints
static const long BSUM_OFF    = 37050004;     // 256 ints
static const long SCAL_OFF    = 37050260;     // 2 doubles (byte off %8==0: even float off)
static const long STATS_OFF   = 37050264;     // 2 floats (mean, alpha)
static const long TOTAL_FLOATS= 37050272;     // ~148.2 MB needed in ws

// ---------------- generic fp32 tiled GEMM: C = act(A[M,K] @ W[K,N] + b) ----
#define BM 64
#define BN 64
#define BK 16

__global__ __launch_bounds__(256) void gemm_bias_act(
    const float* __restrict__ A, int lda,
    const float* __restrict__ W, int ldw,
    const float* __restrict__ bias,
    float* __restrict__ C, int ldc,
    int M, int K, int wmode, int do_relu)
{
    __shared__ float As[BK][BM + 1];
    __shared__ float Bs[BK][BN + 1];
    const int tid = threadIdx.x;
    const int tx = tid & 15, ty = tid >> 4;
    const int row0 = blockIdx.x * BM;
    const int col0 = blockIdx.y * BN;

    float acc[4][4] = {};

    const int lr = tid >> 4;   // 0..15 (A row base)
    const int lk = tid & 15;   // k within tile
    const int bc = tid & 63;   // B col
    const int bk = tid >> 6;   // 0..3

    for (int k0 = 0; k0 < K; k0 += BK) {
        #pragma unroll
        for (int i = 0; i < 4; i++) {
            int m = row0 + lr + i * 16;
            float v = 0.f;
            if (m < M) v = A[(size_t)m * lda + k0 + lk];
            As[lk][lr + i * 16] = v;
        }
        #pragma unroll
        for (int i = 0; i < 4; i++) {
            int k = bk + i * 4;
            float v = W[(size_t)(k0 + k) * ldw + col0 + bc];
            if (wmode) v = fmaxf(2.f * v, 0.f);   // parsing = relu(2*P)
            Bs[k][bc] = v;
        }
        __syncthreads();
        #pragma unroll
        for (int kk = 0; kk < BK; kk++) {
            float a[4], b[4];
            #pragma unroll
            for (int i = 0; i < 4; i++) a[i] = As[kk][ty * 4 + i];
            #pragma unroll
            for (int j = 0; j < 4; j++) b[j] = Bs[kk][tx * 4 + j];
            #pragma unroll
            for (int i = 0; i < 4; i++)
                #pragma unroll
                for (int j = 0; j < 4; j++)
                    acc[i][j] = fmaf(a[i], b[j], acc[i][j]);
        }
        __syncthreads();
    }
    #pragma unroll
    for (int i = 0; i < 4; i++) {
        int m = row0 + ty * 4 + i;
        if (m >= M) continue;
        #pragma unroll
        for (int j = 0; j < 4; j++) {
            int n = col0 + tx * 4 + j;
            float v = acc[i][j] + (bias ? bias[n] : 0.f);
            if (do_relu) v = fmaxf(v, 0.f);
            C[(size_t)m * ldc + n] = v;
        }
    }
}

// ---------------- edge weight: ew_raw[e] = dot(pe[col], logits[row]) -------
__global__ __launch_bounds__(256) void edge_ew_kernel(
    const int* __restrict__ ei, const float* __restrict__ logits,
    const float* __restrict__ pe, float* __restrict__ ew_raw,
    double* __restrict__ S)
{
    const int tid = threadIdx.x;
    const int e = blockIdx.x * 256 + tid;
    double v = 0.0, v2 = 0.0;
    if (e < NEDGES) {
        int r = ei[e];
        int c = ei[NEDGES + e];
        const float4* lr = (const float4*)(logits + (size_t)r * CD);
        const float4* pc = (const float4*)(pe + (size_t)c * CD);
        float acc = 0.f;
        #pragma unroll
        for (int k = 0; k < CD / 4; k++) {
            float4 a = lr[k], b = pc[k];
            acc += a.x * b.x + a.y * b.y + a.z * b.z + a.w * b.w;
        }
        ew_raw[e] = acc;
        v = acc; v2 = (double)acc * (double)acc;
    }
    __shared__ double s1[256], s2[256];
    s1[tid] = v; s2[tid] = v2;
    __syncthreads();
    for (int s = 128; s > 0; s >>= 1) {
        if (tid < s) { s1[tid] += s1[tid + s]; s2[tid] += s2[tid + s]; }
        __syncthreads();
    }
    if (tid == 0) {
        atomicAdd(&S[0], s1[0]);
        atomicAdd(&S[1], s2[0]);
    }
}

__global__ void stats_kernel(const double* __restrict__ S, float* __restrict__ st)
{
    double E = (double)NEDGES;
    double mean = S[0] / E;
    double var = (S[1] - S[0] * S[0] / E) / (E - 1.0);
    st[0] = (float)mean;
    st[1] = (float)sqrt(1e-4 / var);
}

// ew[e] = (raw-mean)*alpha + 1 ; deg[col]+=ew ; cnt[col]+=1
__global__ __launch_bounds__(256) void edge_norm_kernel(
    const int* __restrict__ ei, const float* __restrict__ ew_raw,
    const float* __restrict__ st, float* __restrict__ ew,
    float* __restrict__ deg, int* __restrict__ cnt)
{
    int e = blockIdx.x * 256 + threadIdx.x;
    if (e >= NEDGES) return;
    float w = (ew_raw[e] - st[0]) * st[1] + 1.0f;
    ew[e] = w;
    int c = ei[NEDGES + e];
    atomicAdd(&deg[c], w);
    atomicAdd(&cnt[c], 1);
}

__global__ __launch_bounds__(256) void dis_kernel(
    const float* __restrict__ deg, float* __restrict__ dis)
{
    int i = blockIdx.x * 256 + threadIdx.x;
    if (i >= NNODES) return;
    float d = deg[i] + 1.0f;   // self-loop weight 1
    dis[i] = (d > 0.f) ? rsqrtf(d) : 0.f;
}

// ---------------- CSR build: scan over per-node counts --------------------
__global__ __launch_bounds__(256) void scan1_kernel(
    const int* __restrict__ cnt, int* __restrict__ incl, int* __restrict__ bsum)
{
    __shared__ int s[256];
    int t = threadIdx.x;
    int i = blockIdx.x * 256 + t;
    int v = (i < NNODES) ? cnt[i] : 0;
    s[t] = v;
    __syncthreads();
    for (int off = 1; off < 256; off <<= 1) {
        int u = (t >= off) ? s[t - off] : 0;
        __syncthreads();
        s[t] += u;
        __syncthreads();
    }
    if (i < NNODES) incl[i] = s[t];
    if (t == 255) bsum[blockIdx.x] = s[255];
}

__global__ __launch_bounds__(256) void scan2_kernel(int* __restrict__ bsum, int nb)
{
    __shared__ int s[256];
    int t = threadIdx.x;
    int v = (t < nb) ? bsum[t] : 0;
    s[t] = v;
    __syncthreads();
    for (int off = 1; off < 256; off <<= 1) {
        int u = (t >= off) ? s[t - off] : 0;
        __syncthreads();
        s[t] += u;
        __syncthreads();
    }
    if (t < nb) bsum[t] = s[t] - v;   // exclusive block offset
}

__global__ __launch_bounds__(256) void scan3_kernel(
    const int* __restrict__ cnt, const int* __restrict__ incl,
    const int* __restrict__ bsum, int* __restrict__ rowptr, int* __restrict__ woff)
{
    int i = blockIdx.x * 256 + threadIdx.x;
    if (i >= NNODES) return;
    int off = bsum[blockIdx.x];
    int r = incl[i] - cnt[i] + off;
    rowptr[i] = r;
    woff[i] = r;
    if (i == NNODES - 1) rowptr[NNODES] = incl[i] + off;
}

__global__ __launch_bounds__(256) void scatter_kernel(
    const int* __restrict__ ei, const float* __restrict__ ew,
    const float* __restrict__ dis, int* __restrict__ woff,
    int* __restrict__ csr_row, float* __restrict__ csr_w)
{
    int e = blockIdx.x * 256 + threadIdx.x;
    if (e >= NEDGES) return;
    int r = ei[e];
    int c = ei[NEDGES + e];
    int p = atomicAdd(&woff[c], 1);
    csr_row[p] = r;
    csr_w[p] = dis[r] * ew[e] * dis[c];
}

// ---------------- weighted aggregation: out[n] = relu(Σ w·xw[row] + dn²·xw[n] + b)
__global__ __launch_bounds__(128) void agg_kernel(
    const float* __restrict__ xw, const float* __restrict__ dis,
    const int* __restrict__ rowptr, const int* __restrict__ csr_row,
    const float* __restrict__ csr_w, const float* __restrict__ bias,
    float* __restrict__ out, int ldo)
{
    int n = blockIdx.x;
    int f = threadIdx.x;
    float dn = dis[n];
    float acc = dn * dn * xw[(size_t)n * HD + f];
    int s = rowptr[n], e = rowptr[n + 1];
    for (int j = s; j < e; j++) {
        int r = csr_row[j];
        float w = csr_w[j];
        acc += w * xw[(size_t)r * HD + f];
    }
    out[(size_t)n * ldo + f] = fmaxf(acc + bias[f], 0.f);
}

// ---------------- launch --------------------------------------------------
extern "C" void kernel_launch(void* const* d_in, const int* in_sizes, int n_in,
                              void* d_out, int out_size, void* d_ws, size_t ws_size,
                              hipStream_t stream)
{
    const float* x   = (const float*)d_in[0];
    const int*   ei  = (const int*)d_in[1];
    const float* Wp1 = (const float*)d_in[2];
    const float* bp1 = (const float*)d_in[3];
    const float* Wp2 = (const float*)d_in[4];
    const float* bp2 = (const float*)d_in[5];
    const float* Wp3 = (const float*)d_in[6];
    const float* bp3 = (const float*)d_in[7];
    const float* P0  = (const float*)d_in[8];
    const float* Wg0 = (const float*)d_in[9];
    const float* bg0 = (const float*)d_in[10];
    const float* Wg1 = (const float*)d_in[11];
    const float* bg1 = (const float*)d_in[12];
    // d_in[13], d_in[14] = Wg2/bg2: dead in reference (JK break before append)
    const float* Wl1 = (const float*)d_in[15];
    const float* bl1 = (const float*)d_in[16];
    const float* Wl2 = (const float*)d_in[17];
    const float* bl2 = (const float*)d_in[18];
    float* out = (float*)d_out;

    float* ws = (float*)d_ws;
    float*  h1      = ws + H1_OFF;
    float*  xw      = ws + XW_OFF;
    float*  xj      = ws + XJ_OFF;
    float*  hid     = ws + HID_OFF;
    float*  h2      = ws + H2_OFF;
    int*    csr_row = (int*)(ws + CSR_ROW_OFF);
    float*  csr_w   = ws + CSR_W_OFF;
    float*  logits  = ws + LOGITS_OFF;
    float*  pe      = ws + PE_OFF;
    float*  ew_raw  = ws + EWR_OFF;
    int*    scan_tmp= (int*)(ws + EWR_OFF);  // reuse after ew_raw consumed
    float*  ew      = ws + EW_OFF;
    float*  deg     = ws + DEG_OFF;
    float*  dis     = ws + DIS_OFF;
    int*    cnt     = (int*)(ws + CNT_OFF);
    int*    rowptr  = (int*)(ws + RP_OFF);
    int*    woff    = (int*)(ws + WOFF_OFF);
    int*    bsum    = (int*)(ws + BSUM_OFF);
    double* S       = (double*)(ws + SCAL_OFF);
    float*  st      = ws + STATS_OFF;

    const int MT = (NNODES + BM - 1) / BM;          // 782 row tiles
    const int EB = (NEDGES + 255) / 256;            // 3125
    const int NB = (NNODES + 255) / 256;            // 196

    // zero deg/dis/cnt/rowptr/woff/bsum/scalars in one memset
    hipMemsetAsync(ws + DEG_OFF, 0, (size_t)(TOTAL_FLOATS - DEG_OFF) * 4, stream);

    // --- edge-weight MLP ---
    gemm_bias_act<<<dim3(MT, 8), 256, 0, stream>>>(x, IND, Wp1, 512, bp1, h1, 512, NNODES, IND, 0, 1);
    gemm_bias_act<<<dim3(MT, 1), 256, 0, stream>>>(h1, 512, Wp2, 64, bp2, h2, 64, NNODES, 512, 0, 1);
    gemm_bias_act<<<dim3(MT, 1), 256, 0, stream>>>(h2, 64, Wp3, 64, bp3, logits, 64, NNODES, 64, 0, 0);
    // pe = logits @ relu(2*P0)
    gemm_bias_act<<<dim3(MT, 1), 256, 0, stream>>>(logits, 64, P0, 64, nullptr, pe, 64, NNODES, 64, 1, 0);

    // --- per-edge weights + stats ---
    edge_ew_kernel<<<EB, 256, 0, stream>>>(ei, logits, pe, ew_raw, S);
    stats_kernel<<<1, 1, 0, stream>>>(S, st);
    edge_norm_kernel<<<EB, 256, 0, stream>>>(ei, ew_raw, st, ew, deg, cnt);
    dis_kernel<<<NB, 256, 0, stream>>>(deg, dis);

    // --- CSR build (col-sorted) ---
    scan1_kernel<<<NB, 256, 0, stream>>>(cnt, scan_tmp, bsum);
    scan2_kernel<<<1, 256, 0, stream>>>(bsum, NB);
    scan3_kernel<<<NB, 256, 0, stream>>>(cnt, scan_tmp, bsum, rowptr, woff);
    scatter_kernel<<<EB, 256, 0, stream>>>(ei, ew, dis, woff, csr_row, csr_w);

    // --- GCN layer 0: x1 = relu(agg(x @ Wg0) + bg0) -> xj[:, 0:128] ---
    gemm_bias_act<<<dim3(MT, 2), 256, 0, stream>>>(x, IND, Wg0, HD, nullptr, xw, HD, NNODES, IND, 0, 0);
    agg_kernel<<<NNODES, HD, 0, stream>>>(xw, dis, rowptr, csr_row, csr_w, bg0, xj, 2 * HD);

    // --- GCN layer 1: x2 = relu(agg(x1 @ Wg1) + bg1) -> xj[:, 128:256] ---
    gemm_bias_act<<<dim3(MT, 2), 256, 0, stream>>>(xj, 2 * HD, Wg1, HD, nullptr, xw, HD, NNODES, HD, 0, 0);
    agg_kernel<<<NNODES, HD, 0, stream>>>(xw, dis, rowptr, csr_row, csr_w, bg1, xj + HD, 2 * HD);

    // --- JK head ---
    gemm_bias_act<<<dim3(MT, 2), 256, 0, stream>>>(xj, 2 * HD, Wl1, HD, bl1, hid, HD, NNODES, 2 * HD, 0, 1);
    gemm_bias_act<<<dim3(MT, 1), 256, 0, stream>>>(hid, HD, Wl2, CD, bl2, out, CD, NNODES, HD, 0, 0);
}

// Round 2
// 789.616 us; speedup vs baseline: 2.0831x; 2.0831x over previous
//
#include <hip/hip_runtime.h>
#include <hip/hip_bf16.h>
#include <cmath>

#define NNODES 50000
#define NEDGES 800000
#define IND    512
#define HD     128
#define CD     64

typedef __bf16 bf16x8 __attribute__((ext_vector_type(8)));
typedef float  f32x4  __attribute__((ext_vector_type(4)));

// ---------------- workspace layout (byte offsets) ----------------
// region X: xb (bf16 50000x512 = 51.2MB); dead after G2 -> xj (bf16 50000x256) + hid (bf16 50000x128)
static const size_t XB_B   = 0;
static const size_t XJ_B   = 0;
static const size_t HID_B  = 25600000;
// region H: h1 (bf16 50000x512 = 51.2MB); dead after G3 -> xw (fp32 50000x128)
static const size_t H1_B   = 51200000;
static const size_t XW_B   = 51200000;
static const size_t H2_B   = 102400000;   // bf16 50000x64
static const size_t LG_B   = 108800000;   // bf16 50000x64 (logits)
static const size_t PE_B   = 115200000;   // fp32 50000x64
static const size_t WT_B   = 128000000;   // transposed bf16 weights, 851968 B
static const size_t EWR_B  = 128852000;   // fp32 800000
static const size_t EW_B   = 132052000;   // fp32 800000
static const size_t CSRR_B = 135252000;   // int 800000
static const size_t CSRW_B = 138452000;   // fp32 800000
static const size_t DEG_B  = 141652000;   // fp32 50000   (zero block start)
static const size_t CNT_B  = 141852000;   // int 50000
static const size_t S_B    = 142052000;   // 2 doubles
static const size_t ZERO_BYTES = 400016;  // deg + cnt + S
static const size_t DIS_B  = 142052016;   // fp32 50000
static const size_t INCL_B = 142252016;   // int 50000
static const size_t RP_B   = 142452016;   // int 50001
static const size_t WOFF_B = 142652032;   // int 50000
static const size_t BSUM_B = 142852032;   // int 256
static const size_t ST_B   = 142853056;   // 2 floats
// total ~142.86 MB

// weight sub-offsets (bytes within WT_B)
static const size_t WP1T_O = 0;       // 512x512
static const size_t WG0T_O = 524288;  // 128x512
static const size_t WP2T_O = 655360;  // 64x512
static const size_t WP3T_O = 720896;  // 64x64
static const size_t P0T_O  = 729088;  // 64x64 (relu(2x) applied)
static const size_t WG1T_O = 737280;  // 128x128
static const size_t WL1T_O = 770048;  // 128x256
static const size_t WL2T_O = 835584;  // 64x128

// ---------------- weight transpose+cast: dst[n*K+k] = cvt(f(src[k*N+n])) ----
struct WD { const float* s; __hip_bfloat16* d; int K; int N; int mode; };
struct WP { WD w[8]; };

__global__ __launch_bounds__(256) void transpose_cast_all(WP p)
{
    WD d = p.w[blockIdx.y];
    int i = blockIdx.x * 256 + threadIdx.x;
    if (i >= d.K * d.N) return;
    int k = i % d.K, n = i / d.K;
    float v = d.s[(size_t)k * d.N + n];
    if (d.mode) v = fmaxf(2.f * v, 0.f);
    d.d[i] = __float2bfloat16(v);
}

// ---------------- cast x -> bf16 (8 elems/thread) --------------------------
__global__ __launch_bounds__(256) void cast_x_kernel(
    const float* __restrict__ x, __hip_bfloat16* __restrict__ xb, long n)
{
    long i = ((long)blockIdx.x * 256 + threadIdx.x) * 8;
    if (i >= n) return;
    float4 a = *(const float4*)(x + i);
    float4 b = *(const float4*)(x + i + 4);
    __hip_bfloat16 o[8] __attribute__((aligned(16)));
    o[0] = __float2bfloat16(a.x); o[1] = __float2bfloat16(a.y);
    o[2] = __float2bfloat16(a.z); o[3] = __float2bfloat16(a.w);
    o[4] = __float2bfloat16(b.x); o[5] = __float2bfloat16(b.y);
    o[6] = __float2bfloat16(b.z); o[7] = __float2bfloat16(b.w);
    *(int4*)(xb + i) = *(const int4*)o;
}

// ---------------- bf16 MFMA GEMM: C = act(A[M,K] @ Bt[N,K]^T + bias) -------
// BM=128 fixed; 4 waves; wave tile WM=64 x WN. BN = 2*WN. K % 32 == 0, N % BN == 0.
template<int BN, int WN>
__global__ __launch_bounds__(256) void gemm_mfma(
    const __hip_bfloat16* __restrict__ A, int lda,
    const __hip_bfloat16* __restrict__ Bt, int ldb,
    const float* __restrict__ bias,
    void* __restrict__ Cout, int ldc,
    int M, int K, int do_relu, int out_bf16)
{
    constexpr int BF = WN / 16;
    constexpr int BPASS = BN / 64;             // staging passes for B tile
    __shared__ __bf16 As[128 * 40];            // [128 rows][32 k + 8 pad]
    __shared__ __bf16 Bs[BN * 40];

    const int t = threadIdx.x;
    const int row0 = blockIdx.y * 128;
    const int col0 = blockIdx.x * BN;

    const int wv   = t >> 6;
    const int lane = t & 63;
    const int quad = lane >> 4;
    const int l16  = lane & 15;
    const int wrow = (wv >> 1) * 64;
    const int wcol = (wv & 1) * WN;

    f32x4 acc[4][BF] = {};

    for (int k0 = 0; k0 < K; k0 += 32) {
        #pragma unroll
        for (int p = 0; p < 2; p++) {
            int idx = t + p * 256;
            int r = idx >> 2, kg = (idx & 3) * 8;
            int m = row0 + r;
            int4 v = make_int4(0, 0, 0, 0);
            if (m < M) v = *(const int4*)(A + (size_t)m * lda + k0 + kg);
            *(int4*)&As[r * 40 + kg] = v;
        }
        #pragma unroll
        for (int p = 0; p < BPASS; p++) {
            int idx = t + p * 256;
            int r = idx >> 2, kg = (idx & 3) * 8;
            int4 v = *(const int4*)(Bt + (size_t)(col0 + r) * ldb + k0 + kg);
            *(int4*)&Bs[r * 40 + kg] = v;
        }
        __syncthreads();

        bf16x8 af[4], bfr[BF];
        #pragma unroll
        for (int i = 0; i < 4; i++)
            af[i] = *(const bf16x8*)&As[(wrow + i * 16 + l16) * 40 + quad * 8];
        #pragma unroll
        for (int j = 0; j < BF; j++)
            bfr[j] = *(const bf16x8*)&Bs[(wcol + j * 16 + l16) * 40 + quad * 8];
        #pragma unroll
        for (int i = 0; i < 4; i++)
            #pragma unroll
            for (int j = 0; j < BF; j++)
                acc[i][j] = __builtin_amdgcn_mfma_f32_16x16x32_bf16(af[i], bfr[j], acc[i][j], 0, 0, 0);
        __syncthreads();
    }

    // epilogue: C[row=quad*4+reg (+16*i +wrow), col=l16 (+16*j +wcol)]
    #pragma unroll
    for (int i = 0; i < 4; i++) {
        #pragma unroll
        for (int j = 0; j < BF; j++) {
            int n = col0 + wcol + j * 16 + l16;
            float bv = bias ? bias[n] : 0.f;
            #pragma unroll
            for (int reg = 0; reg < 4; reg++) {
                int m = row0 + wrow + i * 16 + quad * 4 + reg;
                if (m >= M) continue;
                float v = acc[i][j][reg] + bv;
                if (do_relu) v = fmaxf(v, 0.f);
                if (out_bf16)
                    ((__hip_bfloat16*)Cout)[(size_t)m * ldc + n] = __float2bfloat16(v);
                else
                    ((float*)Cout)[(size_t)m * ldc + n] = v;
            }
        }
    }
}

// ---------------- edge weight: ew_raw[e] = dot(logits[row], pe[col]) -------
__global__ __launch_bounds__(256) void edge_ew_kernel(
    const int* __restrict__ ei, const __hip_bfloat16* __restrict__ logits,
    const float* __restrict__ pe, float* __restrict__ ew_raw,
    double* __restrict__ S)
{
    const int tid = threadIdx.x;
    const int e = blockIdx.x * 256 + tid;
    double v = 0.0, v2 = 0.0;
    if (e < NEDGES) {
        int r = ei[e];
        int c = ei[NEDGES + e];
        const __hip_bfloat16* lr = logits + (size_t)r * CD;
        const float4* pc = (const float4*)(pe + (size_t)c * CD);
        float acc = 0.f;
        #pragma unroll
        for (int k4 = 0; k4 < CD / 4; k4++) {
            float4 b = pc[k4];
            acc += __bfloat162float(lr[k4 * 4 + 0]) * b.x
                 + __bfloat162float(lr[k4 * 4 + 1]) * b.y
                 + __bfloat162float(lr[k4 * 4 + 2]) * b.z
                 + __bfloat162float(lr[k4 * 4 + 3]) * b.w;
        }
        ew_raw[e] = acc;
        v = acc; v2 = (double)acc * (double)acc;
    }
    __shared__ double s1[256], s2[256];
    s1[tid] = v; s2[tid] = v2;
    __syncthreads();
    for (int s = 128; s > 0; s >>= 1) {
        if (tid < s) { s1[tid] += s1[tid + s]; s2[tid] += s2[tid + s]; }
        __syncthreads();
    }
    if (tid == 0) {
        atomicAdd(&S[0], s1[0]);
        atomicAdd(&S[1], s2[0]);
    }
}

__global__ void stats_kernel(const double* __restrict__ S, float* __restrict__ st)
{
    double E = (double)NEDGES;
    double mean = S[0] / E;
    double var = (S[1] - S[0] * S[0] / E) / (E - 1.0);
    st[0] = (float)mean;
    st[1] = (float)sqrt(1e-4 / var);
}

__global__ __launch_bounds__(256) void edge_norm_kernel(
    const int* __restrict__ ei, const float* __restrict__ ew_raw,
    const float* __restrict__ st, float* __restrict__ ew,
    float* __restrict__ deg, int* __restrict__ cnt)
{
    int e = blockIdx.x * 256 + threadIdx.x;
    if (e >= NEDGES) return;
    float w = (ew_raw[e] - st[0]) * st[1] + 1.0f;
    ew[e] = w;
    int c = ei[NEDGES + e];
    atomicAdd(&deg[c], w);
    atomicAdd(&cnt[c], 1);
}

__global__ __launch_bounds__(256) void dis_kernel(
    const float* __restrict__ deg, float* __restrict__ dis)
{
    int i = blockIdx.x * 256 + threadIdx.x;
    if (i >= NNODES) return;
    float d = deg[i] + 1.0f;   // self-loop weight 1
    dis[i] = (d > 0.f) ? rsqrtf(d) : 0.f;
}

// ---------------- CSR build ------------------------------------------------
__global__ __launch_bounds__(256) void scan1_kernel(
    const int* __restrict__ cnt, int* __restrict__ incl, int* __restrict__ bsum)
{
    __shared__ int s[256];
    int t = threadIdx.x;
    int i = blockIdx.x * 256 + t;
    int v = (i < NNODES) ? cnt[i] : 0;
    s[t] = v;
    __syncthreads();
    for (int off = 1; off < 256; off <<= 1) {
        int u = (t >= off) ? s[t - off] : 0;
        __syncthreads();
        s[t] += u;
        __syncthreads();
    }
    if (i < NNODES) incl[i] = s[t];
    if (t == 255) bsum[blockIdx.x] = s[255];
}

__global__ __launch_bounds__(256) void scan2_kernel(int* __restrict__ bsum, int nb)
{
    __shared__ int s[256];
    int t = threadIdx.x;
    int v = (t < nb) ? bsum[t] : 0;
    s[t] = v;
    __syncthreads();
    for (int off = 1; off < 256; off <<= 1) {
        int u = (t >= off) ? s[t - off] : 0;
        __syncthreads();
        s[t] += u;
        __syncthreads();
    }
    if (t < nb) bsum[t] = s[t] - v;   // exclusive block offset
}

__global__ __launch_bounds__(256) void scan3_kernel(
    const int* __restrict__ cnt, const int* __restrict__ incl,
    const int* __restrict__ bsum, int* __restrict__ rowptr, int* __restrict__ woff)
{
    int i = blockIdx.x * 256 + threadIdx.x;
    if (i >= NNODES) return;
    int off = bsum[blockIdx.x];
    int r = incl[i] - cnt[i] + off;
    rowptr[i] = r;
    woff[i] = r;
    if (i == NNODES - 1) rowptr[NNODES] = incl[i] + off;
}

__global__ __launch_bounds__(256) void scatter_kernel(
    const int* __restrict__ ei, const float* __restrict__ ew,
    const float* __restrict__ dis, int* __restrict__ woff,
    int* __restrict__ csr_row, float* __restrict__ csr_w)
{
    int e = blockIdx.x * 256 + threadIdx.x;
    if (e >= NEDGES) return;
    int r = ei[e];
    int c = ei[NEDGES + e];
    int p = atomicAdd(&woff[c], 1);
    csr_row[p] = r;
    csr_w[p] = dis[r] * ew[e] * dis[c];
}

// ---------------- weighted aggregation (fp32 in, bf16 out) ----------------
__global__ __launch_bounds__(128) void agg_kernel(
    const float* __restrict__ xw, const float* __restrict__ dis,
    const int* __restrict__ rowptr, const int* __restrict__ csr_row,
    const float* __restrict__ csr_w, const float* __restrict__ bias,
    __hip_bfloat16* __restrict__ out, int ldo)
{
    int n = blockIdx.x;
    int f = threadIdx.x;
    float dn = dis[n];
    float acc = dn * dn * xw[(size_t)n * HD + f];
    int s = rowptr[n], e = rowptr[n + 1];
    for (int j = s; j < e; j++) {
        int r = csr_row[j];
        float w = csr_w[j];
        acc += w * xw[(size_t)r * HD + f];
    }
    out[(size_t)n * ldo + f] = __float2bfloat16(fmaxf(acc + bias[f], 0.f));
}

// ---------------- launch --------------------------------------------------
extern "C" void kernel_launch(void* const* d_in, const int* in_sizes, int n_in,
                              void* d_out, int out_size, void* d_ws, size_t ws_size,
                              hipStream_t stream)
{
    const float* x   = (const float*)d_in[0];
    const int*   ei  = (const int*)d_in[1];
    const float* Wp1 = (const float*)d_in[2];
    const float* bp1 = (const float*)d_in[3];
    const float* Wp2 = (const float*)d_in[4];
    const float* bp2 = (const float*)d_in[5];
    const float* Wp3 = (const float*)d_in[6];
    const float* bp3 = (const float*)d_in[7];
    const float* P0  = (const float*)d_in[8];
    const float* Wg0 = (const float*)d_in[9];
    const float* bg0 = (const float*)d_in[10];
    const float* Wg1 = (const float*)d_in[11];
    const float* bg1 = (const float*)d_in[12];
    // d_in[13], d_in[14] = Wg2/bg2: dead in reference
    const float* Wl1 = (const float*)d_in[15];
    const float* bl1 = (const float*)d_in[16];
    const float* Wl2 = (const float*)d_in[17];
    const float* bl2 = (const float*)d_in[18];
    float* out = (float*)d_out;

    char* wsb = (char*)d_ws;
    __hip_bfloat16* xb     = (__hip_bfloat16*)(wsb + XB_B);
    __hip_bfloat16* xj     = (__hip_bfloat16*)(wsb + XJ_B);
    __hip_bfloat16* hid    = (__hip_bfloat16*)(wsb + HID_B);
    __hip_bfloat16* h1     = (__hip_bfloat16*)(wsb + H1_B);
    float*          xw     = (float*)(wsb + XW_B);
    __hip_bfloat16* h2     = (__hip_bfloat16*)(wsb + H2_B);
    __hip_bfloat16* lg     = (__hip_bfloat16*)(wsb + LG_B);
    float*          pe     = (float*)(wsb + PE_B);
    __hip_bfloat16* wt     = (__hip_bfloat16*)(wsb + WT_B);
    float*          ew_raw = (float*)(wsb + EWR_B);
    float*          ew     = (float*)(wsb + EW_B);
    int*            csr_row= (int*)(wsb + CSRR_B);
    float*          csr_w  = (float*)(wsb + CSRW_B);
    float*          deg    = (float*)(wsb + DEG_B);
    int*            cnt    = (int*)(wsb + CNT_B);
    double*         S      = (double*)(wsb + S_B);
    float*          dis    = (float*)(wsb + DIS_B);
    int*            incl   = (int*)(wsb + INCL_B);
    int*            rowptr = (int*)(wsb + RP_B);
    int*            woff   = (int*)(wsb + WOFF_B);
    int*            bsum   = (int*)(wsb + BSUM_B);
    float*          st     = (float*)(wsb + ST_B);

    __hip_bfloat16* Wp1t = (__hip_bfloat16*)(wsb + WT_B + WP1T_O);
    __hip_bfloat16* Wg0t = (__hip_bfloat16*)(wsb + WT_B + WG0T_O);
    __hip_bfloat16* Wp2t = (__hip_bfloat16*)(wsb + WT_B + WP2T_O);
    __hip_bfloat16* Wp3t = (__hip_bfloat16*)(wsb + WT_B + WP3T_O);
    __hip_bfloat16* P0t  = (__hip_bfloat16*)(wsb + WT_B + P0T_O);
    __hip_bfloat16* Wg1t = (__hip_bfloat16*)(wsb + WT_B + WG1T_O);
    __hip_bfloat16* Wl1t = (__hip_bfloat16*)(wsb + WT_B + WL1T_O);
    __hip_bfloat16* Wl2t = (__hip_bfloat16*)(wsb + WT_B + WL2T_O);

    const int EB = (NEDGES + 255) / 256;            // 3125
    const int NB = (NNODES + 255) / 256;            // 196
    const int MT = (NNODES + 127) / 128;            // 391 row tiles

    hipMemsetAsync(wsb + DEG_B, 0, ZERO_BYTES, stream);

    // --- prep: weight transpose+cast, x cast ---
    WP wp;
    wp.w[0] = { Wp1, Wp1t, 512, 512, 0 };
    wp.w[1] = { Wg0, Wg0t, 512, 128, 0 };
    wp.w[2] = { Wp2, Wp2t, 512,  64, 0 };
    wp.w[3] = { Wp3, Wp3t,  64,  64, 0 };
    wp.w[4] = { P0,  P0t,   64,  64, 1 };   // relu(2*P)
    wp.w[5] = { Wg1, Wg1t, 128, 128, 0 };
    wp.w[6] = { Wl1, Wl1t, 256, 128, 0 };
    wp.w[7] = { Wl2, Wl2t, 128,  64, 0 };
    transpose_cast_all<<<dim3(1024, 8), 256, 0, stream>>>(wp);
    cast_x_kernel<<<12500, 256, 0, stream>>>(x, xb, (long)NNODES * IND);

    // --- edge-weight MLP (bf16 MFMA) ---
    gemm_mfma<128, 64><<<dim3(4, MT), 256, 0, stream>>>(xb, 512, Wp1t, 512, bp1, h1, 512, NNODES, 512, 1, 1);
    gemm_mfma<64, 32><<<dim3(1, MT), 256, 0, stream>>>(h1, 512, Wp2t, 512, bp2, h2, 64, NNODES, 512, 1, 1);
    gemm_mfma<64, 32><<<dim3(1, MT), 256, 0, stream>>>(h2, 64, Wp3t, 64, bp3, lg, 64, NNODES, 64, 0, 1);
    gemm_mfma<64, 32><<<dim3(1, MT), 256, 0, stream>>>(lg, 64, P0t, 64, nullptr, pe, 64, NNODES, 64, 0, 0);

    // --- per-edge weights + stats ---
    edge_ew_kernel<<<EB, 256, 0, stream>>>(ei, lg, pe, ew_raw, S);
    stats_kernel<<<1, 1, 0, stream>>>(S, st);
    edge_norm_kernel<<<EB, 256, 0, stream>>>(ei, ew_raw, st, ew, deg, cnt);
    dis_kernel<<<NB, 256, 0, stream>>>(deg, dis);

    // --- CSR build (col-sorted) ---
    scan1_kernel<<<NB, 256, 0, stream>>>(cnt, incl, bsum);
    scan2_kernel<<<1, 256, 0, stream>>>(bsum, NB);
    scan3_kernel<<<NB, 256, 0, stream>>>(cnt, incl, bsum, rowptr, woff);
    scatter_kernel<<<EB, 256, 0, stream>>>(ei, ew, dis, woff, csr_row, csr_w);

    // --- GCN layer 0: xw = x @ Wg0 (fp32 out, overlays h1 which is now dead) ---
    gemm_mfma<128, 64><<<dim3(1, MT), 256, 0, stream>>>(xb, 512, Wg0t, 512, nullptr, xw, 128, NNODES, 512, 0, 0);
    agg_kernel<<<NNODES, HD, 0, stream>>>(xw, dis, rowptr, csr_row, csr_w, bg0, xj, 2 * HD);

    // --- GCN layer 1 ---
    gemm_mfma<128, 64><<<dim3(1, MT), 256, 0, stream>>>(xj, 2 * HD, Wg1t, 128, nullptr, xw, 128, NNODES, 128, 0, 0);
    agg_kernel<<<NNODES, HD, 0, stream>>>(xw, dis, rowptr, csr_row, csr_w, bg1, xj + HD, 2 * HD);

    // --- JK head ---
    gemm_mfma<128, 64><<<dim3(1, MT), 256, 0, stream>>>(xj, 2 * HD, Wl1t, 256, bl1, hid, 128, NNODES, 256, 1, 1);
    gemm_mfma<64, 32><<<dim3(1, MT), 256, 0, stream>>>(hid, 128, Wl2t, 128, bl2, out, 64, NNODES, 128, 0, 0);
}